// Round 13
// baseline (154.233 us; speedup 1.0000x reference)
//
#include <hip/hip_runtime.h>
#include <hip/hip_bf16.h>

#define N 8192
#define D_IN 512
#define D_OUT 64
#define ALPHA 0.2f
#define BM 16
#define NSPLIT 4
#define KSEG (N / NSPLIT)       // 2048 cols per split
#define NSH (KSEG / 128)        // 16 steps; wave covers 32 of each 128 cols/step
#define REPM 4                  // DIAGNOSTIC: isolate pure-read stream rate

typedef __attribute__((ext_vector_type(4))) float f32x4;
typedef __attribute__((ext_vector_type(8))) short bf16x8;

static __device__ __forceinline__ unsigned pk_bf16(float lo, float hi) {
    unsigned ulo = __bfloat16_as_ushort(__float2bfloat16(lo));
    unsigned uhi = __bfloat16_as_ushort(__float2bfloat16(hi));
    return (uhi << 16) | ulo;
}

// DIAGNOSTIC kernel: pure adj read stream -> 1 bit/elem (writes only 8 MB).
// REPM x repeat so it surfaces in rocprof top-5 with its own counters.
__global__ __launch_bounds__(256) void gat_mask_kernel(
    const float* __restrict__ adj, unsigned char* __restrict__ msk)
{
    for (int rep = 0; rep < REPM; ++rep) {
        size_t wave = ((size_t)blockIdx.x * 256 + threadIdx.x) >> 6;
        int lane = threadIdx.x & 63;
#pragma unroll
        for (int it = 0; it < 8; ++it) {
            size_t fo = (wave * 8 + it) * 512 + (size_t)lane * 8;
            float4 v0 = *(const float4*)(adj + fo);
            float4 v1 = *(const float4*)(adj + fo + 4);
            unsigned b =  (unsigned)(v0.x > 0.f)
                       | ((unsigned)(v0.y > 0.f) << 1)
                       | ((unsigned)(v0.z > 0.f) << 2)
                       | ((unsigned)(v0.w > 0.f) << 3)
                       | ((unsigned)(v1.x > 0.f) << 4)
                       | ((unsigned)(v1.y > 0.f) << 5)
                       | ((unsigned)(v1.z > 0.f) << 6)
                       | ((unsigned)(v1.w > 0.f) << 7);
            msk[fo >> 3] = (unsigned char)b;
        }
    }
}

// Kernel 1: h = input @ W -> pre-swizzled MFMA B-frags (hpk) + s1/s2 (R11/R12).
__global__ __launch_bounds__(256) void gat_h_kernel(
    const float* __restrict__ input, const float* __restrict__ W,
    const float* __restrict__ a, unsigned short* __restrict__ hpk,
    float* __restrict__ s1, float* __restrict__ s2)
{
    __shared__ float hp[4][4][64];
    int ws   = threadIdx.x >> 6;
    int lane = threadIdx.x & 63;
    int row0 = blockIdx.x * 4;
    const float* in0 = input + (size_t)row0 * D_IN + ws * 128;
    const float* Wp  = W + ws * 128 * D_OUT;
    float acc[4] = {0.f, 0.f, 0.f, 0.f};
#pragma unroll 4
    for (int k = 0; k < 128; ++k) {
        float wk = Wp[k * D_OUT + lane];
#pragma unroll
        for (int r = 0; r < 4; ++r)
            acc[r] = fmaf(in0[r * D_IN + k], wk, acc[r]);
    }
#pragma unroll
    for (int r = 0; r < 4; ++r) hp[ws][r][lane] = acc[r];
    __syncthreads();
    if (ws == 0) {
        float h[4];
#pragma unroll
        for (int r = 0; r < 4; ++r)
            h[r] = (hp[0][r][lane] + hp[1][r][lane]) + (hp[2][r][lane] + hp[3][r][lane]);
        int kw = row0 >> 5, kb = (row0 >> 3) & 3, e0 = row0 & 7;
        int dw = lane >> 4, dd = lane & 15;
        size_t off = ((size_t)((kw * 4 + dw) * 64) + kb * 16 + dd) * 8 + e0;
        uint2 hv;
        hv.x = pk_bf16(h[0], h[1]);
        hv.y = pk_bf16(h[2], h[3]);
        *(uint2*)(hpk + off) = hv;
        float a1 = a[lane], a2 = a[D_OUT + lane];
#pragma unroll
        for (int r = 0; r < 4; ++r) {
            float p1 = h[r] * a1;
            float p2 = h[r] * a2;
#pragma unroll
            for (int off2 = 32; off2; off2 >>= 1) {
                p1 += __shfl_xor(p1, off2, 64);
                p2 += __shfl_xor(p2, off2, 64);
            }
            if (lane == 0) { s1[row0 + r] = p1; s2[row0 + r] = p2; }
        }
    }
}

struct ADP { float4 a0, a1; };          // adj 32B/lane for one step's own rows
struct SSP { float4 sA, sB; };          // s2 pair for one 32-col slice
struct UBP { uint4 b0, b1, b2, b3; };   // 4 d-window B-frags for one 32-k window

// Kernel 2 (FUSED, step-interleaved): per step p, each wave loads ITS 4 rows x
// 128 cols of adj for step p+3 (2 float4/lane, coalesced), converts step p+1's
// (2-iter-old) loads to mask bits -> triple-buffered 256B LDS slice, ONE
// barrier, then computes step p (mask byte from LDS, w=exp(leaky-e), 4 MFMA
// with hpk B-frags). HBM sees a continuous 2-step-deep stream; no monolithic
// phases. Split-K x4 partials out.
__global__ __launch_bounds__(256) void gat_flash_kernel(
    const float* __restrict__ adj, const unsigned short* __restrict__ hpk,
    const float* __restrict__ s1, const float* __restrict__ s2,
    float* __restrict__ pacc, float* __restrict__ plsum)
{
    __shared__ unsigned char ml[3][BM * 16];   // 768 B: [buf][row*16 + colchunk]
    __shared__ float Cl[4][BM][D_OUT];         // 16 KB combine (end only)
    __shared__ float lsl[4][BM];

    const int tid  = threadIdx.x;
    const int lane = tid & 63;
    const int ws   = tid >> 6;
    const int i    = lane & 15;          // A-frag row
    const int kb   = lane >> 4;          // k-subwindow
    const int hf   = blockIdx.x >> 9;    // k-split 0..3
    const int rb   = blockIdx.x & 511;   // row-block
    const int rg   = rb * BM + i;

    // loader mapping: this wave loads rows ws*4..+4; lane covers (lr, 8 cols)
    const int lr = ws * 4 + (lane >> 4);
    const int lc = lane & 15;
    const float* arow = adj + (size_t)(rb * BM + lr) * N + hf * KSEG + lc * 8;
    const float* s2b  = s2 + hf * KSEG + ws * 32 + kb * 8;
    const unsigned short* hb = hpk + (((size_t)(hf * 64 + ws)) << 11) + (lane << 3);

    float s1r  = s1[rg];
    float eref = s1r + s2[rg];                    // diagonal logit (adj[i][i]=1)
    eref = eref > 0.f ? eref : ALPHA * eref;      // leaky_relu
    float lsum = 0.f;
    f32x4 acc0 = {0,0,0,0}, acc1 = {0,0,0,0}, acc2 = {0,0,0,0}, acc3 = {0,0,0,0};

    auto issue_a = [&](ADP& d, int ps) {
        d.a0 = *(const float4*)(arow + ps * 128);
        d.a1 = *(const float4*)(arow + ps * 128 + 4);
    };
    auto cvt_write = [&](const ADP& d, int buf) {
        unsigned b =  (unsigned)(d.a0.x > 0.f)
                   | ((unsigned)(d.a0.y > 0.f) << 1)
                   | ((unsigned)(d.a0.z > 0.f) << 2)
                   | ((unsigned)(d.a0.w > 0.f) << 3)
                   | ((unsigned)(d.a1.x > 0.f) << 4)
                   | ((unsigned)(d.a1.y > 0.f) << 5)
                   | ((unsigned)(d.a1.z > 0.f) << 6)
                   | ((unsigned)(d.a1.w > 0.f) << 7);
        ml[buf][lr * 16 + lc] = (unsigned char)b;
    };
    auto issue_s = [&](SSP& p, int ps) {
        p.sA = *(const float4*)(s2b + ps * 128);
        p.sB = *(const float4*)(s2b + ps * 128 + 4);
    };
    auto issue_u = [&](UBP& p, int ps) {
        const unsigned short* f = hb + ((size_t)ps << 13);
        p.b0 = *(const uint4*)(f);
        p.b1 = *(const uint4*)(f + 512);
        p.b2 = *(const uint4*)(f + 1024);
        p.b3 = *(const uint4*)(f + 1536);
    };
    auto compute = [&](const SSP& p, const UBP& u, unsigned m) {
        const float* sv0 = (const float*)&p.sA;
        const float* sv1 = (const float*)&p.sB;
        float w[8];
#pragma unroll
        for (int z = 0; z < 4; ++z) {
            float e0 = s1r + sv0[z]; e0 = e0 > 0.f ? e0 : ALPHA * e0;
            float e1 = s1r + sv1[z]; e1 = e1 > 0.f ? e1 : ALPHA * e1;
            float w0 = __expf(e0 - eref);
            float w1 = __expf(e1 - eref);
            w[z]     = ((m >> z) & 1u)       ? w0 : 0.f;
            w[z + 4] = ((m >> (z + 4)) & 1u) ? w1 : 0.f;
        }
#pragma unroll
        for (int z = 0; z < 8; ++z) lsum += w[z];
        uint4 pk;
        pk.x = pk_bf16(w[0], w[1]); pk.y = pk_bf16(w[2], w[3]);
        pk.z = pk_bf16(w[4], w[5]); pk.w = pk_bf16(w[6], w[7]);
        bf16x8 A = __builtin_bit_cast(bf16x8, pk);
        acc0 = __builtin_amdgcn_mfma_f32_16x16x32_bf16(A, __builtin_bit_cast(bf16x8, u.b0), acc0, 0, 0, 0);
        acc1 = __builtin_amdgcn_mfma_f32_16x16x32_bf16(A, __builtin_bit_cast(bf16x8, u.b1), acc1, 0, 0, 0);
        acc2 = __builtin_amdgcn_mfma_f32_16x16x32_bf16(A, __builtin_bit_cast(bf16x8, u.b2), acc2, 0, 0, 0);
        acc3 = __builtin_amdgcn_mfma_f32_16x16x32_bf16(A, __builtin_bit_cast(bf16x8, u.b3), acc3, 0, 0, 0);
    };

    // prologue: loads for steps 0 (Dp), 1 (D0), 2 (D1); S/U for 0,1
    ADP Dp, D0, D1; SSP S0, S1; UBP U0, U1;
    issue_a(Dp, 0); issue_a(D0, 1); issue_a(D1, 2);
    issue_s(S0, 0); issue_u(U0, 0);
    issue_s(S1, 1); issue_u(U1, 1);
    cvt_write(Dp, 0);
    __syncthreads();                      // ml[0] ready

    int wbuf = 1, rbuf = 0;               // rotating triple-buffer indices
    for (int q = 0; q < NSH; q += 2) {
        // ---- iteration q (uses D0/S0/U0) ----
        if (q + 1 < NSH) cvt_write(D0, wbuf);           // data loaded 2 iters ago
        if (q + 3 < NSH) issue_a(D0, q + 3);
        __syncthreads();                                 // ml[wbuf] ready
        {
            unsigned m = ml[rbuf][i * 16 + ws * 4 + kb];
            compute(S0, U0, m);
        }
        if (q + 2 < NSH) { issue_s(S0, q + 2); issue_u(U0, q + 2); }
        rbuf = wbuf; wbuf = (wbuf == 2) ? 0 : wbuf + 1;
        // ---- iteration q+1 (uses D1/S1/U1) ----
        if (q + 2 < NSH) cvt_write(D1, wbuf);
        if (q + 4 < NSH) issue_a(D1, q + 4);
        __syncthreads();
        {
            unsigned m = ml[rbuf][i * 16 + ws * 4 + kb];
            compute(S1, U1, m);
        }
        if (q + 3 < NSH) { issue_s(S1, q + 3); issue_u(U1, q + 3); }
        rbuf = wbuf; wbuf = (wbuf == 2) ? 0 : wbuf + 1;
    }

    // lsum: lanes i, i+16, i+32, i+48 hold row-i k-slices of this wave
    lsum += __shfl_xor(lsum, 16, 64);
    lsum += __shfl_xor(lsum, 32, 64);
    if (lane < 16) lsl[ws][lane] = lsum;

    // C k-partials: row = kb*4+reg, col = dw*16+i  (C/D frag layout)
    const f32x4 av[4] = {acc0, acc1, acc2, acc3};
#pragma unroll
    for (int dw = 0; dw < 4; ++dw)
#pragma unroll
        for (int reg = 0; reg < 4; ++reg)
            Cl[ws][kb * 4 + reg][dw * 16 + i] = av[dw][reg];
    __syncthreads();

#pragma unroll
    for (int o = tid; o < BM * D_OUT; o += 256) {
        int row = o >> 6, d = o & 63;
        float v = (Cl[0][row][d] + Cl[1][row][d]) + (Cl[2][row][d] + Cl[3][row][d]);
        pacc[((size_t)hf * N + rb * BM + row) * 64 + d] = v;
    }
    if (tid < BM)
        plsum[hf * N + rb * BM + tid] =
            (lsl[0][tid] + lsl[1][tid]) + (lsl[2][tid] + lsl[3][tid]);
}

// Kernel 3: combine the 4 k-splits, normalize, elu.
__global__ __launch_bounds__(256) void gat_reduce_kernel(
    const float* __restrict__ pacc, const float* __restrict__ plsum,
    float* __restrict__ out)
{
    int idx = blockIdx.x * 256 + threadIdx.x;
    int row = idx >> 6;
    float aa = 0.f, l = 0.f;
#pragma unroll
    for (int hf = 0; hf < NSPLIT; ++hf) {
        aa += pacc[(size_t)hf * N * 64 + idx];
        l  += plsum[hf * N + row];
    }
    float o = aa / l;
    out[idx] = o > 0.f ? o : expm1f(o);
}

extern "C" void kernel_launch(void* const* d_in, const int* in_sizes, int n_in,
                              void* d_out, int out_size, void* d_ws, size_t ws_size,
                              hipStream_t stream) {
    const float* input = (const float*)d_in[0];   // (8192, 512) f32
    const float* adj   = (const float*)d_in[1];   // (8192, 8192) f32
    const float* W     = (const float*)d_in[2];   // (512, 64) f32
    const float* a     = (const float*)d_in[3];   // (128, 1) f32
    float* out = (float*)d_out;                   // (8192, 64) f32

    unsigned short* hpk = (unsigned short*)d_ws;          // 1 MB fragment buffer
    float* s1    = (float*)(hpk + (size_t)N * D_OUT);     // N f32
    float* s2    = s1 + N;                                // N f32
    float* pacc  = s2 + N;                                // NSPLIT*N*64 f32 = 8 MB
    float* plsum = pacc + (size_t)NSPLIT * N * 64;        // NSPLIT*N f32
    unsigned char* msk = (unsigned char*)(plsum + (size_t)NSPLIT * N);  // 8 MB (diag)

    gat_mask_kernel<<<4096, 256, 0, stream>>>(adj, msk);   // DIAGNOSTIC (REPM=4)
    gat_h_kernel<<<2048, 256, 0, stream>>>(input, W, a, hpk, s1, s2);
    gat_flash_kernel<<<512 * NSPLIT, 256, 0, stream>>>(adj, hpk, s1, s2, pacc, plsum);
    gat_reduce_kernel<<<N * 64 / 256, 256, 0, stream>>>(pacc, plsum, out);
}